// Round 1
// baseline (2534.962 us; speedup 1.0000x reference)
//
#include <hip/hip_runtime.h>
#include <hip/hip_bf16.h>

#define NTOK 65536
#define DD 256
#define FF 1024
#define EE 8
#define TM 64

__device__ __forceinline__ unsigned rotl32(unsigned v, int d) {
  return (v << d) | (v >> (32 - d));
}

// JAX threefry2x32, 20 rounds. key = jax.random.key(42) -> (0, 42).
// jax_threefry_partitionable=True (default in modern JAX): counter for flat
// element j is (hi,lo)=(0,j); 32-bit output = x0 ^ x1.
__device__ __forceinline__ unsigned jax_random_bits32(unsigned c0, unsigned c1) {
  const unsigned k0 = 0u, k1 = 42u;
  const unsigned k2 = 0x1BD11BDAu ^ k0 ^ k1;
  unsigned x0 = c0 + k0, x1 = c1 + k1;
#define TFR(r) { x0 += x1; x1 = rotl32(x1, (r)); x1 ^= x0; }
  TFR(13) TFR(15) TFR(26) TFR(6)
  x0 += k1; x1 += k2 + 1u;
  TFR(17) TFR(29) TFR(16) TFR(24)
  x0 += k2; x1 += k0 + 2u;
  TFR(13) TFR(15) TFR(26) TFR(6)
  x0 += k0; x1 += k1 + 3u;
  TFR(17) TFR(29) TFR(16) TFR(24)
  x0 += k1; x1 += k2 + 4u;
  TFR(13) TFR(15) TFR(26) TFR(6)
  x0 += k2; x1 += k0 + 5u;
#undef TFR
  return x0 ^ x1;
}

// One wave per token: fp32 gate dot (8 experts), gumbel-argmax routing,
// atomic bucket scatter.
__global__ __launch_bounds__(256) void gate_route_kernel(
    const float* __restrict__ x, const float* __restrict__ gw,
    const float* __restrict__ gb, int* __restrict__ counts,
    int* __restrict__ buckets, int bstride) {
  const int lane = threadIdx.x & 63;
  const int wv = threadIdx.x >> 6;
  const int t = blockIdx.x * 4 + wv;  // token id, grid exactly covers NTOK

  const float4 x4 = *reinterpret_cast<const float4*>(x + (size_t)t * DD + lane * 4);
  const float xs[4] = {x4.x, x4.y, x4.z, x4.w};
  float acc[EE] = {0.f, 0.f, 0.f, 0.f, 0.f, 0.f, 0.f, 0.f};
#pragma unroll
  for (int j = 0; j < 4; ++j) {
    const float* gwr = gw + (size_t)(lane * 4 + j) * EE;
#pragma unroll
    for (int e = 0; e < EE; ++e) acc[e] = fmaf(xs[j], gwr[e], acc[e]);
  }
  // full-wave butterfly sum: every lane ends with all 8 logits
#pragma unroll
  for (int off = 32; off > 0; off >>= 1) {
#pragma unroll
    for (int e = 0; e < EE; ++e) acc[e] += __shfl_xor(acc[e], off);
  }

  const int e = lane & 7;  // lanes 8..63 mirror lanes 0..7 (harmless)
  float logit = 0.f;
#pragma unroll
  for (int q = 0; q < EE; ++q) logit = (e == q) ? acc[q] : logit;
  logit += gb[e];

  // gumbel element flat index = t*8 + e
  const unsigned bits = jax_random_bits32(0u, (unsigned)(t * EE + e));
  const float f = __uint_as_float((bits >> 9) | 0x3f800000u) - 1.0f;
  const float u = fmaxf(1.17549435e-38f, f);  // JAX uniform(minval=tiny, maxval=1)
  const float g = -logf(-logf(u));
  float val = g + logit;
  int idx = e;
  // argmax over the 8-lane group, first-index tie-break (matches jnp.argmax)
#pragma unroll
  for (int off = 4; off > 0; off >>= 1) {
    const float oval = __shfl_xor(val, off);
    const int oidx = __shfl_xor(idx, off);
    if (oval > val || (oval == val && oidx < idx)) { val = oval; idx = oidx; }
  }
  if (lane == 0) {
    const int pos = atomicAdd(&counts[idx], 1);
    if (pos < bstride) buckets[idx * bstride + pos] = t;
  }
}

// Per (expert, 64-token tile): gather X -> LDS, loop F in chunks of 64:
// GEMM1 (h = relu(X@W1+b1)) -> LDS, GEMM2 (y += h@W2) in registers; scatter.
__global__ __launch_bounds__(512) void ffn_kernel(
    const float* __restrict__ x, const float* __restrict__ w1,
    const float* __restrict__ b1, const float* __restrict__ w2,
    const float* __restrict__ b2, const int* __restrict__ counts,
    const int* __restrict__ buckets, float* __restrict__ out, int bstride) {
  const int e = blockIdx.y;
  const int cnt = min(counts[e], bstride);
  const int m0 = blockIdx.x * TM;
  if (m0 >= cnt) return;

  __shared__ float Xt[DD][TM];   // [d][m]  64 KB
  __shared__ float Ht[64][TM];   // [f][m]  16 KB
  __shared__ int toks[TM];

  const int tid = threadIdx.x;
  if (tid < TM) {
    const int i = m0 + tid;
    toks[tid] = buckets[e * bstride + (i < cnt ? i : cnt - 1)];
  }
  __syncthreads();

  // gather X tile (transposed into LDS)
  for (int idx = tid; idx < TM * (DD / 4); idx += 512) {
    const int r = idx >> 6;    // token row in tile
    const int c4 = idx & 63;   // d-quad
    const float4 v = *reinterpret_cast<const float4*>(
        x + (size_t)toks[r] * DD + c4 * 4);
    Xt[c4 * 4 + 0][r] = v.x;
    Xt[c4 * 4 + 1][r] = v.y;
    Xt[c4 * 4 + 2][r] = v.z;
    Xt[c4 * 4 + 3][r] = v.w;
  }
  __syncthreads();

  const int fg = tid & 15;    // f-quad in chunk (GEMM1)
  const int mg = tid >> 4;    // m-pair 0..31    (GEMM1)
  const int dc = tid & 63;    // d-quad          (GEMM2)
  const int mgrp = tid >> 6;  // m-oct 0..7      (GEMM2)

  float yacc[8][4];
#pragma unroll
  for (int i = 0; i < 8; ++i)
#pragma unroll
    for (int j = 0; j < 4; ++j) yacc[i][j] = 0.f;

  for (int fc0 = 0; fc0 < FF; fc0 += 64) {
    // ---- GEMM1: h[64 tokens][64 f] ----
    float hacc[2][4];
#pragma unroll
    for (int i = 0; i < 2; ++i)
#pragma unroll
      for (int j = 0; j < 4; ++j) hacc[i][j] = 0.f;

    const float* w1p = w1 + (size_t)e * DD * FF + fc0 + fg * 4;
    for (int d = 0; d < DD; ++d) {
      const float4 w = *reinterpret_cast<const float4*>(w1p + (size_t)d * FF);
      const float2 xv = *reinterpret_cast<const float2*>(&Xt[d][mg * 2]);
      const float ws[4] = {w.x, w.y, w.z, w.w};
      const float xl[2] = {xv.x, xv.y};
#pragma unroll
      for (int i = 0; i < 2; ++i)
#pragma unroll
        for (int j = 0; j < 4; ++j)
          hacc[i][j] = fmaf(xl[i], ws[j], hacc[i][j]);
    }
    // bias + relu -> Ht ; previous GEMM2 finished reading Ht at the loop-end barrier
#pragma unroll
    for (int j = 0; j < 4; ++j) {
      const float bb = b1[e * FF + fc0 + fg * 4 + j];
      Ht[fg * 4 + j][mg * 2 + 0] = fmaxf(hacc[0][j] + bb, 0.f);
      Ht[fg * 4 + j][mg * 2 + 1] = fmaxf(hacc[1][j] + bb, 0.f);
    }
    __syncthreads();

    // ---- GEMM2 partial: y[64 tokens][256 d] += h @ W2[fc0:fc0+64][:] ----
    const float* w2p = w2 + (size_t)e * FF * DD + (size_t)fc0 * DD + dc * 4;
    for (int f = 0; f < 64; ++f) {
      const float4 w = *reinterpret_cast<const float4*>(w2p + (size_t)f * DD);
      const float4 h0 = *reinterpret_cast<const float4*>(&Ht[f][mgrp * 8]);
      const float4 h1 = *reinterpret_cast<const float4*>(&Ht[f][mgrp * 8 + 4]);
      const float hs[8] = {h0.x, h0.y, h0.z, h0.w, h1.x, h1.y, h1.z, h1.w};
      const float ws[4] = {w.x, w.y, w.z, w.w};
#pragma unroll
      for (int i = 0; i < 8; ++i)
#pragma unroll
        for (int j = 0; j < 4; ++j)
          yacc[i][j] = fmaf(hs[i], ws[j], yacc[i][j]);
    }
    __syncthreads();
  }

  // epilogue: + b2, scatter to out rows
#pragma unroll
  for (int i = 0; i < 8; ++i) {
    const int r = mgrp * 8 + i;
    if (m0 + r < cnt) {
      float4 o;
      o.x = yacc[i][0] + b2[e * DD + dc * 4 + 0];
      o.y = yacc[i][1] + b2[e * DD + dc * 4 + 1];
      o.z = yacc[i][2] + b2[e * DD + dc * 4 + 2];
      o.w = yacc[i][3] + b2[e * DD + dc * 4 + 3];
      *reinterpret_cast<float4*>(out + (size_t)toks[r] * DD + dc * 4) = o;
    }
  }
}

extern "C" void kernel_launch(void* const* d_in, const int* in_sizes, int n_in,
                              void* d_out, int out_size, void* d_ws, size_t ws_size,
                              hipStream_t stream) {
  const float* x  = (const float*)d_in[0];
  const float* gw = (const float*)d_in[1];
  const float* gb = (const float*)d_in[2];
  const float* w1 = (const float*)d_in[3];
  const float* b1 = (const float*)d_in[4];
  const float* w2 = (const float*)d_in[5];
  const float* b2 = (const float*)d_in[6];
  float* out = (float*)d_out;

  // ws layout: [0,1024) counts (8 ints used), [1024, ...) buckets
  int bstride = 65536;  // worst-case safe
  if (ws_size < 1024 + (size_t)EE * 65536 * 4) bstride = 12288;  // fallback (routing is near-uniform ~8.2k/expert)
  int* counts = (int*)d_ws;
  int* buckets = (int*)((char*)d_ws + 1024);

  hipMemsetAsync(d_ws, 0, 1024, stream);
  hipLaunchKernelGGL(gate_route_kernel, dim3(NTOK / 4), dim3(256), 0, stream,
                     x, gw, gb, counts, buckets, bstride);
  hipLaunchKernelGGL(ffn_kernel, dim3(NTOK / TM, EE), dim3(512), 0, stream,
                     x, w1, b1, w2, b2, counts, buckets, out, bstride);
}

// Round 3
// 217.333 us; speedup vs baseline: 11.6640x; 11.6640x over previous
//
#include <hip/hip_runtime.h>
#include <hip/hip_bf16.h>

#define NTOK 65536
#define DD 256
#define FF 1024
#define EE 8
#define BSTRIDE 12288
#define MAXT (BSTRIDE / 64)

typedef short bh8 __attribute__((ext_vector_type(8)));
typedef float f4 __attribute__((ext_vector_type(4)));

__device__ __forceinline__ unsigned rotl32(unsigned v, int d) {
  return (v << d) | (v >> (32 - d));
}

// JAX threefry2x32, 20 rounds. key = jax.random.key(42) -> (0, 42).
// partitionable: counter for flat element j is (hi,lo)=(0,j); out = x0 ^ x1.
__device__ __forceinline__ unsigned jax_random_bits32(unsigned c0, unsigned c1) {
  const unsigned k0 = 0u, k1 = 42u;
  const unsigned k2 = 0x1BD11BDAu ^ k0 ^ k1;
  unsigned x0 = c0 + k0, x1 = c1 + k1;
#define TFR(r) { x0 += x1; x1 = rotl32(x1, (r)); x1 ^= x0; }
  TFR(13) TFR(15) TFR(26) TFR(6)
  x0 += k1; x1 += k2 + 1u;
  TFR(17) TFR(29) TFR(16) TFR(24)
  x0 += k2; x1 += k0 + 2u;
  TFR(13) TFR(15) TFR(26) TFR(6)
  x0 += k0; x1 += k1 + 3u;
  TFR(17) TFR(29) TFR(16) TFR(24)
  x0 += k1; x1 += k2 + 4u;
  TFR(13) TFR(15) TFR(26) TFR(6)
  x0 += k2; x1 += k0 + 5u;
#undef TFR
  return x0 ^ x1;
}

__device__ __forceinline__ ushort f2bf(float f) {
  union { float f; unsigned u; } c; c.f = f;
  unsigned r = c.u + 0x7fffu + ((c.u >> 16) & 1u);
  return (ushort)(r >> 16);
}

// ---------------- gate + route: 16 lanes/token, 64 tokens/block ----------------
__global__ __launch_bounds__(1024) void gate_route2(
    const float* __restrict__ x, const float* __restrict__ gw,
    const float* __restrict__ gb, int* __restrict__ counts,
    int* __restrict__ buckets) {
  __shared__ float gwt[EE * DD];   // [e][d], 8KB
  __shared__ int hist[EE], sbase[EE];
  __shared__ unsigned char chs[64];
  __shared__ short lps[64];

  const int tid = threadIdx.x;
  if (tid < EE) hist[tid] = 0;
  // stage gw transposed: gwt[e][d] = gw[d][e]
  for (int i = tid; i < DD * EE; i += 1024) {
    const int d = i >> 3, e = i & 7;
    gwt[e * DD + d] = gw[i];
  }
  __syncthreads();

  const int lane = tid & 63;
  const int wave = tid >> 6;
  const int grp = lane >> 4;
  const int gl = lane & 15;
  const int slot = wave * 4 + grp;
  const int t = blockIdx.x * 64 + slot;

  float acc[EE] = {0.f, 0.f, 0.f, 0.f, 0.f, 0.f, 0.f, 0.f};
  const float* xr = x + (size_t)t * DD;
#pragma unroll
  for (int j = 0; j < 4; ++j) {
    const int d0 = j * 64 + gl * 4;
    const float4 xv = *reinterpret_cast<const float4*>(xr + d0);
#pragma unroll
    for (int e = 0; e < EE; ++e) {
      const float4 g = *reinterpret_cast<const float4*>(&gwt[e * DD + d0]);
      acc[e] = fmaf(xv.x, g.x, acc[e]);
      acc[e] = fmaf(xv.y, g.y, acc[e]);
      acc[e] = fmaf(xv.z, g.z, acc[e]);
      acc[e] = fmaf(xv.w, g.w, acc[e]);
    }
  }
  // reduce across the 16-lane group
#pragma unroll
  for (int off = 8; off >= 1; off >>= 1)
#pragma unroll
    for (int e = 0; e < EE; ++e) acc[e] += __shfl_xor(acc[e], off);

  const int e = gl & 7;
  float logit = 0.f;
#pragma unroll
  for (int q = 0; q < EE; ++q) logit = (e == q) ? acc[q] : logit;
  logit += gb[e];

  const unsigned bits = jax_random_bits32(0u, (unsigned)(t * EE + e));
  const float f = __uint_as_float((bits >> 9) | 0x3f800000u) - 1.0f;
  const float u = fmaxf(1.17549435e-38f, f);
  float val = -logf(-logf(u)) + logit;
  int idx = e;
#pragma unroll
  for (int off = 4; off > 0; off >>= 1) {
    const float ov = __shfl_xor(val, off);
    const int oi = __shfl_xor(idx, off);
    if (ov > val || (ov == val && oi < idx)) { val = ov; idx = oi; }
  }
  if (gl == 0) {
    const int lp = atomicAdd(&hist[idx], 1);
    chs[slot] = (unsigned char)idx;
    lps[slot] = (short)lp;
  }
  __syncthreads();
  if (tid < EE) sbase[tid] = atomicAdd(&counts[tid], hist[tid]);
  __syncthreads();
  if (tid < 64) {
    const int ee = chs[tid];
    const int p = sbase[ee] + lps[tid];
    if (p < BSTRIDE) buckets[ee * BSTRIDE + p] = blockIdx.x * 64 + tid;
  }
}

// ---------------- weight transpose + fp32->bf16: dst[e][c][r] = src[e][r][c] ----------------
__global__ __launch_bounds__(256) void transpose_cvt(
    const float* __restrict__ src, ushort* __restrict__ dst, int R, int C) {
  __shared__ float ts[64][65];
  const int e = blockIdx.z;
  const int r0 = blockIdx.y * 64, c0 = blockIdx.x * 64;
  const int tx = threadIdx.x, ty = threadIdx.y;
  const float* s = src + (size_t)e * R * C;
  ushort* d = dst + (size_t)e * R * C;
#pragma unroll
  for (int i = 0; i < 16; ++i)
    ts[ty * 16 + i][tx] = s[(size_t)(r0 + ty * 16 + i) * C + c0 + tx];
  __syncthreads();
#pragma unroll
  for (int i = 0; i < 16; ++i)
    d[(size_t)(c0 + ty * 16 + i) * R + r0 + tx] = f2bf(ts[tx][ty * 16 + i]);
}

// ---------------- MFMA FFN: per (expert, 64-token tile) ----------------
// w1t[e][f][d] bf16 ; w2t[e][d][f] bf16. Operand-swapped MFMAs:
//   GEMM1: D'[f][m] = mfma(W1frag[f][d], Xfrag[m][d])   -> packed 8B Hb writes
//   GEMM2: D''[d][m] = mfma(W2frag[d][f], Hfrag[m][f])  -> float4 out stores
__global__ __launch_bounds__(512) void ffn_mfma(
    const float* __restrict__ x, const ushort* __restrict__ w1t,
    const float* __restrict__ b1, const ushort* __restrict__ w2t,
    const float* __restrict__ b2, const int* __restrict__ counts,
    const int* __restrict__ buckets, float* __restrict__ out) {
  const int e = blockIdx.x & 7;       // expert = id%8 -> pins expert weights per-XCD
  const int tile = blockIdx.x >> 3;
  const int cnt = min(counts[e], BSTRIDE);
  const int m0 = tile * 64;
  if (m0 >= cnt) return;

  __shared__ ushort Xb[64 * 256];   // 32KB, XOR-swizzled rows (512B)
  __shared__ ushort Hb[64 * 128];   // 16KB, XOR-swizzled rows (256B)
  __shared__ int toks[64];

  const int tid = threadIdx.x;
  const int lane = tid & 63;
  const int wid = tid >> 6;           // 0..7
  const int l15 = lane & 15;
  const int kb = lane >> 4;           // 0..3

  if (tid < 64) {
    const int i = m0 + tid;
    toks[tid] = buckets[e * BSTRIDE + (i < cnt ? i : cnt - 1)];
  }
  __syncthreads();

  // gather X tile -> bf16 -> swizzled LDS
#pragma unroll
  for (int it = 0; it < 8; ++it) {
    const int fi = tid + it * 512;
    const int r = fi >> 6, c4 = fi & 63;
    const float4 v = *reinterpret_cast<const float4*>(x + (size_t)toks[r] * DD + c4 * 4);
    ushort4 b;
    b.x = f2bf(v.x); b.y = f2bf(v.y); b.z = f2bf(v.z); b.w = f2bf(v.w);
    const int byte = (r * 512 + c4 * 8) ^ ((r & 7) << 4);
    *reinterpret_cast<ushort4*>(reinterpret_cast<char*>(Xb) + byte) = b;
  }
  __syncthreads();

  f4 yacc[2][4] = {};

#pragma unroll 1
  for (int fc = 0; fc < FF; fc += 128) {
    // ---- GEMM1: this wave computes D'[f = fc+wid*16 .. +16][m = 0..64] ----
    f4 hacc[4] = {};
    const ushort* w1p = w1t + ((size_t)e * FF + fc + wid * 16 + l15) * DD + kb * 8;
#pragma unroll
    for (int ks = 0; ks < 8; ++ks) {  // d-step of 32
      const bh8 af = *reinterpret_cast<const bh8*>(w1p + ks * 32);
#pragma unroll
      for (int m16 = 0; m16 < 4; ++m16) {
        const int m = m16 * 16 + l15;
        const int byte = (m * 512 + (ks * 32 + kb * 8) * 2) ^ ((m & 7) << 4);
        const bh8 bx = *reinterpret_cast<const bh8*>(reinterpret_cast<const char*>(Xb) + byte);
        hacc[m16] = __builtin_amdgcn_mfma_f32_16x16x32_bf16(af, bx, hacc[m16], 0, 0, 0);
      }
    }

    __syncthreads();  // prev chunk's GEMM2 done reading Hb
    // bias + relu + bf16 -> Hb (thread holds 4 consecutive f at fixed m)
    const float4 b1v = *reinterpret_cast<const float4*>(b1 + e * FF + fc + wid * 16 + kb * 4);
    const int f0 = wid * 16 + kb * 4;
#pragma unroll
    for (int m16 = 0; m16 < 4; ++m16) {
      const int m = m16 * 16 + l15;
      ushort4 hv;
      hv.x = f2bf(fmaxf(hacc[m16][0] + b1v.x, 0.f));
      hv.y = f2bf(fmaxf(hacc[m16][1] + b1v.y, 0.f));
      hv.z = f2bf(fmaxf(hacc[m16][2] + b1v.z, 0.f));
      hv.w = f2bf(fmaxf(hacc[m16][3] + b1v.w, 0.f));
      const int byte = (m * 256 + f0 * 2) ^ ((m & 7) << 4);
      *reinterpret_cast<ushort4*>(reinterpret_cast<char*>(Hb) + byte) = hv;
    }
    __syncthreads();

    // ---- GEMM2: D''[d = wid*32 .. +32][m = 0..64] over k=f chunk ----
    const ushort* w2base = w2t + ((size_t)e * DD + wid * 32 + l15) * FF + fc + kb * 8;
#pragma unroll
    for (int ks = 0; ks < 4; ++ks) {  // f-step of 32
      bh8 aw[2];
#pragma unroll
      for (int d16 = 0; d16 < 2; ++d16)
        aw[d16] = *reinterpret_cast<const bh8*>(w2base + (size_t)d16 * 16 * FF + ks * 32);
#pragma unroll
      for (int m16 = 0; m16 < 4; ++m16) {
        const int m = m16 * 16 + l15;
        const int byte = (m * 256 + (ks * 32 + kb * 8) * 2) ^ ((m & 7) << 4);
        const bh8 bh = *reinterpret_cast<const bh8*>(reinterpret_cast<const char*>(Hb) + byte);
        yacc[0][m16] = __builtin_amdgcn_mfma_f32_16x16x32_bf16(aw[0], bh, yacc[0][m16], 0, 0, 0);
        yacc[1][m16] = __builtin_amdgcn_mfma_f32_16x16x32_bf16(aw[1], bh, yacc[1][m16], 0, 0, 0);
      }
    }
  }

  // epilogue: + b2, float4 scatter (thread holds 4 consecutive d at fixed m)
#pragma unroll
  for (int m16 = 0; m16 < 4; ++m16) {
    const int m = m16 * 16 + l15;
    if (m0 + m < cnt) {
      const int tok = toks[m];
#pragma unroll
      for (int d16 = 0; d16 < 2; ++d16) {
        const int d0 = wid * 32 + d16 * 16 + kb * 4;
        const float4 b2v = *reinterpret_cast<const float4*>(b2 + e * DD + d0);
        float4 o;
        o.x = yacc[d16][m16][0] + b2v.x;
        o.y = yacc[d16][m16][1] + b2v.y;
        o.z = yacc[d16][m16][2] + b2v.z;
        o.w = yacc[d16][m16][3] + b2v.w;
        *reinterpret_cast<float4*>(out + (size_t)tok * DD + d0) = o;
      }
    }
  }
}

// ---------------- fallback fp32 FFN (proven in round 1) ----------------
__global__ __launch_bounds__(512) void ffn_fp32(
    const float* __restrict__ x, const float* __restrict__ w1,
    const float* __restrict__ b1, const float* __restrict__ w2,
    const float* __restrict__ b2, const int* __restrict__ counts,
    const int* __restrict__ buckets, float* __restrict__ out, int bstride) {
  const int e = blockIdx.y;
  const int cnt = min(counts[e], bstride);
  const int m0 = blockIdx.x * 64;
  if (m0 >= cnt) return;

  __shared__ float Xt[DD][64];
  __shared__ float Ht[64][64];
  __shared__ int toks[64];

  const int tid = threadIdx.x;
  if (tid < 64) {
    const int i = m0 + tid;
    toks[tid] = buckets[e * bstride + (i < cnt ? i : cnt - 1)];
  }
  __syncthreads();

  for (int idx = tid; idx < 64 * (DD / 4); idx += 512) {
    const int r = idx >> 6;
    const int c4 = idx & 63;
    const float4 v = *reinterpret_cast<const float4*>(x + (size_t)toks[r] * DD + c4 * 4);
    Xt[c4 * 4 + 0][r] = v.x;
    Xt[c4 * 4 + 1][r] = v.y;
    Xt[c4 * 4 + 2][r] = v.z;
    Xt[c4 * 4 + 3][r] = v.w;
  }
  __syncthreads();

  const int fg = tid & 15;
  const int mg = tid >> 4;
  const int dc = tid & 63;
  const int mgrp = tid >> 6;

  float yacc[8][4];
#pragma unroll
  for (int i = 0; i < 8; ++i)
#pragma unroll
    for (int j = 0; j < 4; ++j) yacc[i][j] = 0.f;

  for (int fc0 = 0; fc0 < FF; fc0 += 64) {
    float hacc[2][4];
#pragma unroll
    for (int i = 0; i < 2; ++i)
#pragma unroll
      for (int j = 0; j < 4; ++j) hacc[i][j] = 0.f;

    const float* w1p = w1 + (size_t)e * DD * FF + fc0 + fg * 4;
    for (int d = 0; d < DD; ++d) {
      const float4 w = *reinterpret_cast<const float4*>(w1p + (size_t)d * FF);
      const float2 xv = *reinterpret_cast<const float2*>(&Xt[d][mg * 2]);
      const float ws[4] = {w.x, w.y, w.z, w.w};
      const float xl[2] = {xv.x, xv.y};
#pragma unroll
      for (int i = 0; i < 2; ++i)
#pragma unroll
        for (int j = 0; j < 4; ++j)
          hacc[i][j] = fmaf(xl[i], ws[j], hacc[i][j]);
    }
#pragma unroll
    for (int j = 0; j < 4; ++j) {
      const float bb = b1[e * FF + fc0 + fg * 4 + j];
      Ht[fg * 4 + j][mg * 2 + 0] = fmaxf(hacc[0][j] + bb, 0.f);
      Ht[fg * 4 + j][mg * 2 + 1] = fmaxf(hacc[1][j] + bb, 0.f);
    }
    __syncthreads();

    const float* w2p = w2 + (size_t)e * FF * DD + (size_t)fc0 * DD + dc * 4;
    for (int f = 0; f < 64; ++f) {
      const float4 w = *reinterpret_cast<const float4*>(w2p + (size_t)f * DD);
      const float4 h0 = *reinterpret_cast<const float4*>(&Ht[f][mgrp * 8]);
      const float4 h1 = *reinterpret_cast<const float4*>(&Ht[f][mgrp * 8 + 4]);
      const float hs[8] = {h0.x, h0.y, h0.z, h0.w, h1.x, h1.y, h1.z, h1.w};
      const float ws[4] = {w.x, w.y, w.z, w.w};
#pragma unroll
      for (int i = 0; i < 8; ++i)
#pragma unroll
        for (int j = 0; j < 4; ++j)
          yacc[i][j] = fmaf(hs[i], ws[j], yacc[i][j]);
    }
    __syncthreads();
  }

#pragma unroll
  for (int i = 0; i < 8; ++i) {
    const int r = mgrp * 8 + i;
    if (m0 + r < cnt) {
      float4 o;
      o.x = yacc[i][0] + b2[e * DD + dc * 4 + 0];
      o.y = yacc[i][1] + b2[e * DD + dc * 4 + 1];
      o.z = yacc[i][2] + b2[e * DD + dc * 4 + 2];
      o.w = yacc[i][3] + b2[e * DD + dc * 4 + 3];
      *reinterpret_cast<float4*>(out + (size_t)toks[r] * DD + dc * 4) = o;
    }
  }
}

extern "C" void kernel_launch(void* const* d_in, const int* in_sizes, int n_in,
                              void* d_out, int out_size, void* d_ws, size_t ws_size,
                              hipStream_t stream) {
  const float* x  = (const float*)d_in[0];
  const float* gw = (const float*)d_in[1];
  const float* gb = (const float*)d_in[2];
  const float* w1 = (const float*)d_in[3];
  const float* b1 = (const float*)d_in[4];
  const float* w2 = (const float*)d_in[5];
  const float* b2 = (const float*)d_in[6];
  float* out = (float*)d_out;

  // ws layout: counts @0 (4KB) | buckets @4096 (8*12288*4 = 384KB) |
  //            w1t @512KB (4MB bf16) | w2t @512KB+4MB (4MB bf16)
  int* counts = (int*)d_ws;
  int* buckets = (int*)((char*)d_ws + 4096);
  ushort* w1t = (ushort*)((char*)d_ws + 524288);
  ushort* w2t = (ushort*)((char*)d_ws + 524288 + 4194304);
  const size_t need = 524288 + 2ull * 4194304;

  hipMemsetAsync(d_ws, 0, 4096, stream);
  hipLaunchKernelGGL(gate_route2, dim3(NTOK / 64), dim3(1024), 0, stream,
                     x, gw, gb, counts, buckets);

  if (ws_size >= need) {
    // w1 [e][256][1024] -> w1t [e][1024][256] ; w2 [e][1024][256] -> w2t [e][256][1024]
    hipLaunchKernelGGL(transpose_cvt, dim3(FF / 64, DD / 64, EE), dim3(64, 4), 0, stream,
                       w1, w1t, DD, FF);
    hipLaunchKernelGGL(transpose_cvt, dim3(DD / 64, FF / 64, EE), dim3(64, 4), 0, stream,
                       w2, w2t, FF, DD);
    hipLaunchKernelGGL(ffn_mfma, dim3(MAXT * EE), dim3(512), 0, stream,
                       x, w1t, b1, w2t, b2, counts, buckets, out);
  } else {
    hipLaunchKernelGGL(ffn_fp32, dim3(NTOK / 64, EE), dim3(512), 0, stream,
                       x, w1, b1, w2, b2, counts, buckets, out, BSTRIDE);
  }
}